// Round 2
// baseline (1001.179 us; speedup 1.0000x reference)
//
#include <hip/hip_runtime.h>

#define NN 100000
#define NE 1600000
#define D 64
#define DACT 16

// ---------------- zero workspace region ----------------
__global__ void zero_kernel(float* __restrict__ p, int n) {
    int i = blockIdx.x * blockDim.x + threadIdx.x;
    if (i < n) p[i] = 0.f;
}

// ---------------- degree / dinv ----------------
__global__ void degree_kernel(const int* __restrict__ dst,
                              float* __restrict__ deg, int nEdges) {
    int e = blockIdx.x * blockDim.x + threadIdx.x;
    if (e < nEdges) atomicAdd(&deg[dst[e]], 1.0f);
}

__global__ void dinv_kernel(float* __restrict__ deg, int n) {
    int i = blockIdx.x * blockDim.x + threadIdx.x;
    if (i < n) deg[i] = rsqrtf(deg[i] + 1.0f);
}

// ---------------- GEMM: [n,64] @ [64,64] -> [n,64] ----------------
// 256 threads = 4 nodes x 64 cols. W staged in LDS (16 KB).
__global__ __launch_bounds__(256) void gemm64(const float* __restrict__ X,
                                              const float* __restrict__ W,
                                              float* __restrict__ H, int n) {
    __shared__ float Ws[64][64];
    __shared__ float Xs[4][64];
    int tid = threadIdx.x;
    #pragma unroll
    for (int i = tid; i < 64 * 64; i += 256) Ws[i >> 6][i & 63] = W[i];
    int col = tid & 63, r = tid >> 6;
    int node = blockIdx.x * 4 + r;
    if (node < n) Xs[r][col] = X[node * 64 + col];
    __syncthreads();
    if (node >= n) return;
    float acc = 0.f;
    #pragma unroll
    for (int k = 0; k < 64; ++k) acc += Xs[r][k] * Ws[k][col];
    H[node * 64 + col] = acc;
}

// ---------------- self-loop init: agg = h * dinv^2 ----------------
__global__ void selfinit_kernel(const float* __restrict__ H,
                                const float* __restrict__ dinv,
                                float* __restrict__ agg, int total) {
    int i = blockIdx.x * blockDim.x + threadIdx.x;
    if (i < total) {
        float di = dinv[i >> 6];
        agg[i] = H[i] * di * di;
    }
}

// ---------------- edge scatter: one wave per edge ----------------
__global__ __launch_bounds__(256) void scatter_kernel(
        const int* __restrict__ src, const int* __restrict__ dst,
        const float* __restrict__ dinv, const float* __restrict__ H,
        float* __restrict__ agg, int nEdges) {
    int e = (int)((blockIdx.x * blockDim.x + threadIdx.x) >> 6);
    int lane = threadIdx.x & 63;
    if (e >= nEdges) return;
    int s = src[e];
    int d = dst[e];
    float c = dinv[s] * dinv[d];
    float v = H[s * 64 + lane] * c;
    atomicAdd(&agg[d * 64 + lane], v);
}

// ---------------- bias + relu, in place ----------------
__global__ void biasrelu_kernel(float* __restrict__ agg,
                                const float* __restrict__ b, int total) {
    int i = blockIdx.x * blockDim.x + threadIdx.x;
    if (i < total) agg[i] = fmaxf(agg[i] + b[i & 63], 0.f);
}

// ---------------- FC head: [n,64] @ [64,16] + b -> out ----------------
// 256 threads = 16 nodes x 16 cols.
__global__ __launch_bounds__(256) void gemmfc(const float* __restrict__ X,
                                              const float* __restrict__ W,
                                              const float* __restrict__ b,
                                              float* __restrict__ out, int n) {
    __shared__ float Ws[64][16];
    __shared__ float Xs[16][65];
    int tid = threadIdx.x;
    #pragma unroll
    for (int i = tid; i < 64 * 16; i += 256) Ws[i >> 4][i & 15] = W[i];
    #pragma unroll
    for (int i = tid; i < 16 * 64; i += 256) {
        int rr = i >> 6, cc = i & 63;
        int nn = blockIdx.x * 16 + rr;
        Xs[rr][cc] = (nn < n) ? X[nn * 64 + cc] : 0.f;
    }
    __syncthreads();
    int col = tid & 15, r = tid >> 4;
    int node = blockIdx.x * 16 + r;
    if (node >= n) return;
    float acc = b[col];
    #pragma unroll
    for (int k = 0; k < 64; ++k) acc += Xs[r][k] * Ws[k][col];
    out[node * 16 + col] = acc;
}

extern "C" void kernel_launch(void* const* d_in, const int* in_sizes, int n_in,
                              void* d_out, int out_size, void* d_ws, size_t ws_size,
                              hipStream_t stream) {
    const float* x   = (const float*)d_in[0];
    const int*   ei  = (const int*)d_in[1];   // int32: harness passes integer inputs as int
    const float* W1  = (const float*)d_in[2];
    const float* b1  = (const float*)d_in[3];
    const float* W2  = (const float*)d_in[4];
    const float* b2  = (const float*)d_in[5];
    const float* Wfc = (const float*)d_in[6];
    const float* bfc = (const float*)d_in[7];
    float* out = (float*)d_out;

    const int* src = ei;
    const int* dst = ei + NE;

    // ws layout: dinv [NN] | bufA [NN*64] | bufB [NN*64]   (~51.6 MB)
    float* dinv = (float*)d_ws;
    float* bufA = dinv + NN;
    float* bufB = bufA + (size_t)NN * D;

    const int total = NN * D;

    zero_kernel<<<(NN + 255) / 256, 256, 0, stream>>>(dinv, NN);
    degree_kernel<<<(NE + 255) / 256, 256, 0, stream>>>(dst, dinv, NE);
    dinv_kernel<<<(NN + 255) / 256, 256, 0, stream>>>(dinv, NN);

    // ---- layer 1 ----
    gemm64<<<NN / 4, 256, 0, stream>>>(x, W1, bufA, NN);
    selfinit_kernel<<<(total + 255) / 256, 256, 0, stream>>>(bufA, dinv, bufB, total);
    scatter_kernel<<<(int)(((long long)NE * 64 + 255) / 256), 256, 0, stream>>>(
        src, dst, dinv, bufA, bufB, NE);
    biasrelu_kernel<<<(total + 255) / 256, 256, 0, stream>>>(bufB, b1, total);

    // ---- layer 2 ----
    gemm64<<<NN / 4, 256, 0, stream>>>(bufB, W2, bufA, NN);
    selfinit_kernel<<<(total + 255) / 256, 256, 0, stream>>>(bufA, dinv, bufB, total);
    scatter_kernel<<<(int)(((long long)NE * 64 + 255) / 256), 256, 0, stream>>>(
        src, dst, dinv, bufA, bufB, NE);
    biasrelu_kernel<<<(total + 255) / 256, 256, 0, stream>>>(bufB, b2, total);

    // ---- FC head ----
    gemmfc<<<NN / 16, 256, 0, stream>>>(bufB, Wfc, bfc, out, NN);
}

// Round 3
// 487.093 us; speedup vs baseline: 2.0554x; 2.0554x over previous
//
#include <hip/hip_runtime.h>

#define NN 100000
#define NE 1600000
#define D 64
#define DACT 16
#define NBLK ((NN + 255) / 256)   // 391 scan blocks

// ---------------- zero int region ----------------
__global__ void zeroi_kernel(int* __restrict__ p, int n) {
    int i = blockIdx.x * blockDim.x + threadIdx.x;
    if (i < n) p[i] = 0;
}

// ---------------- degree histogram (int) ----------------
__global__ void degree_kernel(const int* __restrict__ dst,
                              int* __restrict__ cnt, int nEdges) {
    int e = blockIdx.x * blockDim.x + threadIdx.x;
    if (e < nEdges) atomicAdd(&cnt[dst[e]], 1);
}

__global__ void dinv_kernel(const int* __restrict__ cnt,
                            float* __restrict__ dinv, int n) {
    int i = blockIdx.x * blockDim.x + threadIdx.x;
    if (i < n) dinv[i] = rsqrtf((float)cnt[i] + 1.0f);
}

// ---------------- scan 1: per-256-block exclusive scan ----------------
__global__ __launch_bounds__(256) void scan_block(const int* __restrict__ cnt,
                                                  int* __restrict__ outEx,
                                                  int* __restrict__ bsum, int n) {
    __shared__ int buf[2][256];
    int t = threadIdx.x;
    int i = blockIdx.x * 256 + t;
    int v = (i < n) ? cnt[i] : 0;
    int pi = 0;
    buf[0][t] = v;
    __syncthreads();
    for (int off = 1; off < 256; off <<= 1) {
        int add = (t >= off) ? buf[pi][t - off] : 0;
        buf[1 - pi][t] = buf[pi][t] + add;
        pi ^= 1;
        __syncthreads();
    }
    int incl = buf[pi][t];
    if (i < n) outEx[i] = incl - v;
    if (t == 255) bsum[blockIdx.x] = incl;
}

// ---------------- scan 2: scan the 391 block sums (1 block) ----------------
__global__ __launch_bounds__(512) void scan_top(int* __restrict__ bsum, int nb) {
    __shared__ int buf[2][512];
    int t = threadIdx.x;
    int v = (t < nb) ? bsum[t] : 0;
    int pi = 0;
    buf[0][t] = v;
    __syncthreads();
    for (int off = 1; off < 512; off <<= 1) {
        int add = (t >= off) ? buf[pi][t - off] : 0;
        buf[1 - pi][t] = buf[pi][t] + add;
        pi ^= 1;
        __syncthreads();
    }
    if (t < nb) bsum[t] = buf[pi][t] - v;   // exclusive, in place
}

// ---------------- scan 3: add block offsets ----------------
__global__ void scan_add(int* __restrict__ next, const int* __restrict__ bsum, int n) {
    int i = blockIdx.x * blockDim.x + threadIdx.x;
    if (i < n) next[i] += bsum[i >> 8];
}

// ---------------- placement: counting-sort edges by dst ----------------
// next[] starts as exclusive scan (row_start); after this it equals inclusive
// scan (row_end), which the gather uses: seg d = [d?next[d-1]:0, next[d]).
__global__ void place_kernel(const int* __restrict__ src, const int* __restrict__ dst,
                             int* __restrict__ next, int* __restrict__ esrc, int nEdges) {
    int e = blockIdx.x * blockDim.x + threadIdx.x;
    if (e < nEdges) {
        int p = atomicAdd(&next[dst[e]], 1);
        esrc[p] = src[e];
    }
}

// ---------------- fused gather: agg + self-loop + bias + relu ----------------
// one wave per dst node, lane = feature column
__global__ __launch_bounds__(256) void gather_kernel(
        const int* __restrict__ next, const int* __restrict__ esrc,
        const float* __restrict__ dinv, const float* __restrict__ H,
        const float* __restrict__ b, float* __restrict__ outH, int n) {
    int node = (int)((blockIdx.x * blockDim.x + threadIdx.x) >> 6);
    int lane = threadIdx.x & 63;
    if (node >= n) return;
    int j  = node ? next[node - 1] : 0;
    int e1 = next[node];
    float dd  = dinv[node];
    float acc = H[node * 64 + lane] * dd;   // self loop (×dd again at end)
    for (; j + 3 < e1; j += 4) {
        int sA = esrc[j], sB = esrc[j + 1], sC = esrc[j + 2], sD = esrc[j + 3];
        float vA = H[sA * 64 + lane] * dinv[sA];
        float vB = H[sB * 64 + lane] * dinv[sB];
        float vC = H[sC * 64 + lane] * dinv[sC];
        float vD = H[sD * 64 + lane] * dinv[sD];
        acc += (vA + vB) + (vC + vD);
    }
    for (; j < e1; ++j) {
        int s = esrc[j];
        acc += H[s * 64 + lane] * dinv[s];
    }
    acc = acc * dd + b[lane];
    outH[node * 64 + lane] = fmaxf(acc, 0.f);
}

// ---------------- GEMM: [n,64] @ [64,64], 16 nodes/block, 4 cols/thread ----------------
__global__ __launch_bounds__(256) void gemm64v2(const float* __restrict__ X,
                                                const float* __restrict__ W,
                                                float* __restrict__ H, int n) {
    __shared__ float4 Ws[64][16];
    __shared__ float  Xs[16][68];   // row stride 68: banks (r*4+k)%32 — conflict-free broadcast
    int tid = threadIdx.x;
    // stage W: 1024 float4s, 4 per thread
    const float4* W4 = (const float4*)W;
    #pragma unroll
    for (int i = tid; i < 64 * 16; i += 256) Ws[i >> 4][i & 15] = W4[i];
    // stage X: 16 rows x 64 = 256 float4s, 1 per thread
    {
        int rr = tid >> 4, q = tid & 15;
        int node = blockIdx.x * 16 + rr;
        float4 v = ((const float4*)(X + (size_t)node * 64))[q];
        *(float4*)&Xs[rr][q * 4] = v;
    }
    __syncthreads();
    int r = tid >> 4, cq = tid & 15;
    float4 acc = {0.f, 0.f, 0.f, 0.f};
    #pragma unroll
    for (int k = 0; k < 64; ++k) {
        float x  = Xs[r][k];
        float4 w = Ws[k][cq];
        acc.x += x * w.x; acc.y += x * w.y; acc.z += x * w.z; acc.w += x * w.w;
    }
    int node = blockIdx.x * 16 + r;
    ((float4*)(H + (size_t)node * 64))[cq] = acc;
}

// ---------------- FC head: [n,64] @ [64,16] + b ----------------
__global__ __launch_bounds__(256) void gemmfc(const float* __restrict__ X,
                                              const float* __restrict__ W,
                                              const float* __restrict__ b,
                                              float* __restrict__ out, int n) {
    __shared__ float Ws[64][16];
    __shared__ float Xs[16][65];
    int tid = threadIdx.x;
    #pragma unroll
    for (int i = tid; i < 64 * 16; i += 256) Ws[i >> 4][i & 15] = W[i];
    #pragma unroll
    for (int i = tid; i < 16 * 64; i += 256) {
        int rr = i >> 6, cc = i & 63;
        int nn = blockIdx.x * 16 + rr;
        Xs[rr][cc] = (nn < n) ? X[nn * 64 + cc] : 0.f;
    }
    __syncthreads();
    int col = tid & 15, r = tid >> 4;
    int node = blockIdx.x * 16 + r;
    if (node >= n) return;
    float acc = b[col];
    #pragma unroll
    for (int k = 0; k < 64; ++k) acc += Xs[r][k] * Ws[k][col];
    out[node * 16 + col] = acc;
}

extern "C" void kernel_launch(void* const* d_in, const int* in_sizes, int n_in,
                              void* d_out, int out_size, void* d_ws, size_t ws_size,
                              hipStream_t stream) {
    const float* x   = (const float*)d_in[0];
    const int*   ei  = (const int*)d_in[1];
    const float* W1  = (const float*)d_in[2];
    const float* b1  = (const float*)d_in[3];
    const float* W2  = (const float*)d_in[4];
    const float* b2  = (const float*)d_in[5];
    const float* Wfc = (const float*)d_in[6];
    const float* bfc = (const float*)d_in[7];
    float* out = (float*)d_out;

    const int* src = ei;
    const int* dst = ei + NE;

    // ws: dinv[NN]f | cnt[NN]i | next[NN]i | bsum[512]i | esrc[NE]i | bufA | bufB  (~58.8 MB)
    float* dinv = (float*)d_ws;
    int*   cnt  = (int*)(dinv + NN);
    int*   next = cnt + NN;
    int*   bsum = next + NN;
    int*   esrc = bsum + 512;
    float* bufA = (float*)(esrc + NE);
    float* bufB = bufA + (size_t)NN * D;

    // ---- CSR build ----
    zeroi_kernel<<<NBLK, 256, 0, stream>>>(cnt, NN);
    degree_kernel<<<(NE + 255) / 256, 256, 0, stream>>>(dst, cnt, NE);
    dinv_kernel<<<NBLK, 256, 0, stream>>>(cnt, dinv, NN);
    scan_block<<<NBLK, 256, 0, stream>>>(cnt, next, bsum, NN);
    scan_top<<<1, 512, 0, stream>>>(bsum, NBLK);
    scan_add<<<NBLK, 256, 0, stream>>>(next, bsum, NN);
    place_kernel<<<(NE + 255) / 256, 256, 0, stream>>>(src, dst, next, esrc, NE);

    // ---- layer 1 ----
    gemm64v2<<<NN / 16, 256, 0, stream>>>(x, W1, bufA, NN);
    gather_kernel<<<(NN * 64) / 256, 256, 0, stream>>>(next, esrc, dinv, bufA, b1, bufB, NN);

    // ---- layer 2 ----
    gemm64v2<<<NN / 16, 256, 0, stream>>>(bufB, W2, bufA, NN);
    gather_kernel<<<(NN * 64) / 256, 256, 0, stream>>>(next, esrc, dinv, bufA, b2, bufB, NN);

    // ---- FC head ----
    gemmfc<<<NN / 16, 256, 0, stream>>>(bufB, Wfc, bfc, out, NN);
}

// Round 4
// 377.296 us; speedup vs baseline: 2.6536x; 1.2910x over previous
//
#include <hip/hip_runtime.h>

#define NN 100000
#define NE 1600000
#define D 64
#define NB 391              // ceil(NN/256) buckets of 256 dst nodes
#define NBP 512             // padded bucket count (pow2 for scans)
#define CHUNK 8192
#define NCHUNK ((NE + CHUNK - 1) / CHUNK)   // 196

// ---------------- A0: zero bucket counters ----------------
__global__ void zero_bkt(int* __restrict__ cnt) {
    int t = blockIdx.x * blockDim.x + threadIdx.x;
    if (t < NBP) cnt[t] = 0;
}

// ---------------- A1: bucket histogram (LDS-combined) ----------------
__global__ __launch_bounds__(256) void bkt_hist(const int* __restrict__ dst,
                                                int* __restrict__ cnt) {
    __shared__ int h[NBP];
    int t = threadIdx.x;
    for (int i = t; i < NBP; i += 256) h[i] = 0;
    __syncthreads();
    int base = blockIdx.x * CHUNK;
    int end = min(base + CHUNK, NE);
    for (int e = base + t; e < end; e += 256) atomicAdd(&h[dst[e] >> 8], 1);
    __syncthreads();
    for (int i = t; i < NBP; i += 256) if (h[i]) atomicAdd(&cnt[i], h[i]);
}

// ---------------- A2: scan bucket counts -> base, next ----------------
__global__ __launch_bounds__(512) void bkt_scan(const int* __restrict__ cnt,
                                                int* __restrict__ base,
                                                int* __restrict__ nxt) {
    __shared__ int buf[2][512];
    int t = threadIdx.x;
    int v = cnt[t];
    int pi = 0;
    buf[0][t] = v;
    __syncthreads();
    for (int off = 1; off < 512; off <<= 1) {
        int add = (t >= off) ? buf[pi][t - off] : 0;
        buf[1 - pi][t] = buf[pi][t] + add;
        pi ^= 1;
        __syncthreads();
    }
    int ex = buf[pi][t] - v;
    base[t] = ex;
    nxt[t] = ex;
    if (t == 511) base[512] = buf[pi][511];   // == NE
}

// ---------------- A3: bucket placement with LDS binning ----------------
// Stages a CHUNK of edges in LDS ordered by bucket, then writes each
// bucket-run contiguously (consecutive lanes -> consecutive addresses).
__global__ __launch_bounds__(512) void bkt_place(const int* __restrict__ src,
                                                 const int* __restrict__ dst,
                                                 int* __restrict__ bnext,
                                                 int* __restrict__ pairs) {
    __shared__ int stage[CHUNK];     // packed src | dstLow<<17
    __shared__ int sbuf[2][512];
    __shared__ int lcnt[512];
    __shared__ int lex[512];
    __shared__ int gbase[512];
    __shared__ int lnext[512];
    int t = threadIdx.x;
    int base = blockIdx.x * CHUNK;
    int end = min(base + CHUNK, NE);
    int cc = end - base;
    lcnt[t] = 0;
    __syncthreads();
    for (int e = base + t; e < end; e += 512) atomicAdd(&lcnt[dst[e] >> 8], 1);
    __syncthreads();
    int v = lcnt[t];
    int pi = 0;
    sbuf[0][t] = v;
    __syncthreads();
    for (int off = 1; off < 512; off <<= 1) {
        int add = (t >= off) ? sbuf[pi][t - off] : 0;
        sbuf[1 - pi][t] = sbuf[pi][t] + add;
        pi ^= 1;
        __syncthreads();
    }
    int ex = sbuf[pi][t] - v;
    lex[t] = ex;
    lnext[t] = ex;
    gbase[t] = v ? atomicAdd(&bnext[t], v) : 0;
    __syncthreads();
    for (int e = base + t; e < end; e += 512) {
        int d = dst[e];
        int b = d >> 8;
        int r = atomicAdd(&lnext[b], 1);
        stage[r] = src[e] | ((d & 255) << 17);
    }
    __syncthreads();
    for (int i = t; i < cc; i += 512) {
        // largest b with lex[b] <= i  (zero-width empty buckets resolve right)
        int lo = 0, hi = 511;
        while (lo < hi) {
            int mid = (lo + hi + 1) >> 1;
            if (lex[mid] <= i) lo = mid; else hi = mid - 1;
        }
        pairs[gbase[lo] + (i - lex[lo])] = stage[i];
    }
}

// ---------------- B: per-bucket CSR build + dinv ----------------
// One workgroup per bucket: node histogram (= degree), scan, place esrc.
// Random writes confined to this bucket's ~16KB window on ONE XCD.
__global__ __launch_bounds__(256) void bkt_csr(const int* __restrict__ pairs,
                                               const int* __restrict__ base,
                                               int* __restrict__ next,
                                               float* __restrict__ dinv,
                                               int* __restrict__ esrc) {
    __shared__ int cnt[256];
    __shared__ int sbuf[2][256];
    __shared__ int nxt[256];
    int b = blockIdx.x;
    int e0 = base[b], e1 = base[b + 1];
    int t = threadIdx.x;
    cnt[t] = 0;
    __syncthreads();
    for (int i = e0 + t; i < e1; i += 256) atomicAdd(&cnt[pairs[i] >> 17], 1);
    __syncthreads();
    int v = cnt[t];
    int pi = 0;
    sbuf[0][t] = v;
    __syncthreads();
    for (int off = 1; off < 256; off <<= 1) {
        int add = (t >= off) ? sbuf[pi][t - off] : 0;
        sbuf[1 - pi][t] = sbuf[pi][t] + add;
        pi ^= 1;
        __syncthreads();
    }
    int incl = sbuf[pi][t];
    int node = b * 256 + t;
    if (node < NN) {
        next[node] = e0 + incl;                 // inclusive row end (global CSR)
        dinv[node] = rsqrtf((float)v + 1.0f);   // degree falls out for free
    }
    nxt[t] = e0 + incl - v;
    __syncthreads();
    for (int i = e0 + t; i < e1; i += 256) {
        int w = pairs[i];
        int p = atomicAdd(&nxt[w >> 17], 1);
        esrc[p] = w & 0x1FFFF;
    }
}

// ---------------- fused gather: agg + self-loop + bias + relu ----------------
__global__ __launch_bounds__(256) void gather_kernel(
        const int* __restrict__ next, const int* __restrict__ esrc,
        const float* __restrict__ dinv, const float* __restrict__ H,
        const float* __restrict__ b, float* __restrict__ outH, int n) {
    int node = (int)((blockIdx.x * blockDim.x + threadIdx.x) >> 6);
    int lane = threadIdx.x & 63;
    if (node >= n) return;
    int j  = node ? next[node - 1] : 0;
    int e1 = next[node];
    float dd  = dinv[node];
    float acc = H[node * 64 + lane] * dd;
    for (; j + 3 < e1; j += 4) {
        int sA = esrc[j], sB = esrc[j + 1], sC = esrc[j + 2], sD = esrc[j + 3];
        float vA = H[sA * 64 + lane] * dinv[sA];
        float vB = H[sB * 64 + lane] * dinv[sB];
        float vC = H[sC * 64 + lane] * dinv[sC];
        float vD = H[sD * 64 + lane] * dinv[sD];
        acc += (vA + vB) + (vC + vD);
    }
    for (; j < e1; ++j) {
        int s = esrc[j];
        acc += H[s * 64 + lane] * dinv[s];
    }
    acc = acc * dd + b[lane];
    outH[node * 64 + lane] = fmaxf(acc, 0.f);
}

// ---------------- GEMM: [n,64] @ [64,64], 16 nodes/block, 4 cols/thread ----------------
__global__ __launch_bounds__(256) void gemm64v2(const float* __restrict__ X,
                                                const float* __restrict__ W,
                                                float* __restrict__ H, int n) {
    __shared__ float4 Ws[64][16];
    __shared__ float  Xs[16][68];
    int tid = threadIdx.x;
    const float4* W4 = (const float4*)W;
    #pragma unroll
    for (int i = tid; i < 64 * 16; i += 256) Ws[i >> 4][i & 15] = W4[i];
    {
        int rr = tid >> 4, q = tid & 15;
        int node = blockIdx.x * 16 + rr;
        float4 v = ((const float4*)(X + (size_t)node * 64))[q];
        *(float4*)&Xs[rr][q * 4] = v;
    }
    __syncthreads();
    int r = tid >> 4, cq = tid & 15;
    float4 acc = {0.f, 0.f, 0.f, 0.f};
    #pragma unroll
    for (int k = 0; k < 64; ++k) {
        float x  = Xs[r][k];
        float4 w = Ws[k][cq];
        acc.x += x * w.x; acc.y += x * w.y; acc.z += x * w.z; acc.w += x * w.w;
    }
    int node = blockIdx.x * 16 + r;
    ((float4*)(H + (size_t)node * 64))[cq] = acc;
}

// ---------------- FC head: [n,64] @ [64,16] + b ----------------
__global__ __launch_bounds__(256) void gemmfc(const float* __restrict__ X,
                                              const float* __restrict__ W,
                                              const float* __restrict__ b,
                                              float* __restrict__ out, int n) {
    __shared__ float Ws[64][16];
    __shared__ float Xs[16][65];
    int tid = threadIdx.x;
    #pragma unroll
    for (int i = tid; i < 64 * 16; i += 256) Ws[i >> 4][i & 15] = W[i];
    #pragma unroll
    for (int i = tid; i < 16 * 64; i += 256) {
        int rr = i >> 6, cc = i & 63;
        int nn = blockIdx.x * 16 + rr;
        Xs[rr][cc] = (nn < n) ? X[nn * 64 + cc] : 0.f;
    }
    __syncthreads();
    int col = tid & 15, r = tid >> 4;
    int node = blockIdx.x * 16 + r;
    if (node >= n) return;
    float acc = b[col];
    #pragma unroll
    for (int k = 0; k < 64; ++k) acc += Xs[r][k] * Ws[k][col];
    out[node * 16 + col] = acc;
}

extern "C" void kernel_launch(void* const* d_in, const int* in_sizes, int n_in,
                              void* d_out, int out_size, void* d_ws, size_t ws_size,
                              hipStream_t stream) {
    const float* x   = (const float*)d_in[0];
    const int*   ei  = (const int*)d_in[1];
    const float* W1  = (const float*)d_in[2];
    const float* b1  = (const float*)d_in[3];
    const float* W2  = (const float*)d_in[4];
    const float* b2  = (const float*)d_in[5];
    const float* Wfc = (const float*)d_in[6];
    const float* bfc = (const float*)d_in[7];
    float* out = (float*)d_out;

    const int* src = ei;
    const int* dst = ei + NE;

    // ws: dinv[NN]f | bcnt[512] | bbase[513] | bnext[512] | next[NN] | esrc[NE] | bufA | bufB
    // pairs aliases bufA (CSR build finishes before gemm writes bufA, stream-ordered)
    float* dinv  = (float*)d_ws;
    int*   bcnt  = (int*)(dinv + NN);
    int*   bbase = bcnt + NBP;
    int*   bnext = bbase + NBP + 1;
    int*   next  = bnext + NBP;
    int*   esrc  = next + NN;
    float* bufA  = (float*)(esrc + NE);
    float* bufB  = bufA + (size_t)NN * D;
    int*   pairs = (int*)bufA;

    // ---- CSR build (two-pass counting sort) ----
    zero_bkt<<<2, 256, 0, stream>>>(bcnt);
    bkt_hist<<<NCHUNK, 256, 0, stream>>>(dst, bcnt);
    bkt_scan<<<1, 512, 0, stream>>>(bcnt, bbase, bnext);
    bkt_place<<<NCHUNK, 512, 0, stream>>>(src, dst, bnext, pairs);
    bkt_csr<<<NB, 256, 0, stream>>>(pairs, bbase, next, dinv, esrc);

    // ---- layer 1 ----
    gemm64v2<<<NN / 16, 256, 0, stream>>>(x, W1, bufA, NN);
    gather_kernel<<<(NN * 64) / 256, 256, 0, stream>>>(next, esrc, dinv, bufA, b1, bufB, NN);

    // ---- layer 2 ----
    gemm64v2<<<NN / 16, 256, 0, stream>>>(bufB, W2, bufA, NN);
    gather_kernel<<<(NN * 64) / 256, 256, 0, stream>>>(next, esrc, dinv, bufA, b2, bufB, NN);

    // ---- FC head ----
    gemmfc<<<NN / 16, 256, 0, stream>>>(bufB, Wfc, bfc, out, NN);
}

// Round 5
// 316.202 us; speedup vs baseline: 3.1663x; 1.1932x over previous
//
#include <hip/hip_runtime.h>

#define NN 100000
#define NE 1600000
#define D 64
#define NB 391              // ceil(NN/256) buckets of 256 dst nodes
#define NBP 512             // padded bucket count (pow2 for scans)
#define CHUNK 8192
#define NCHUNK ((NE + CHUNK - 1) / CHUNK)   // 196

static __device__ __forceinline__ unsigned short f2bf(float f) {
    unsigned u = __float_as_uint(f);
    u += 0x7fffu + ((u >> 16) & 1u);   // RNE
    return (unsigned short)(u >> 16);
}

// ---------------- A0: zero bucket counters ----------------
__global__ void zero_bkt(int* __restrict__ cnt) {
    int t = blockIdx.x * blockDim.x + threadIdx.x;
    if (t < NBP) cnt[t] = 0;
}

// ---------------- A1: bucket histogram (LDS-combined) ----------------
__global__ __launch_bounds__(256) void bkt_hist(const int* __restrict__ dst,
                                                int* __restrict__ cnt) {
    __shared__ int h[NBP];
    int t = threadIdx.x;
    for (int i = t; i < NBP; i += 256) h[i] = 0;
    __syncthreads();
    int base = blockIdx.x * CHUNK;
    int end = min(base + CHUNK, NE);
    for (int e = base + t; e < end; e += 256) atomicAdd(&h[dst[e] >> 8], 1);
    __syncthreads();
    for (int i = t; i < NBP; i += 256) if (h[i]) atomicAdd(&cnt[i], h[i]);
}

// ---------------- A2: scan bucket counts -> base, next ----------------
__global__ __launch_bounds__(512) void bkt_scan(const int* __restrict__ cnt,
                                                int* __restrict__ base,
                                                int* __restrict__ nxt) {
    __shared__ int buf[2][512];
    int t = threadIdx.x;
    int v = cnt[t];
    int pi = 0;
    buf[0][t] = v;
    __syncthreads();
    for (int off = 1; off < 512; off <<= 1) {
        int add = (t >= off) ? buf[pi][t - off] : 0;
        buf[1 - pi][t] = buf[pi][t] + add;
        pi ^= 1;
        __syncthreads();
    }
    int ex = buf[pi][t] - v;
    base[t] = ex;
    nxt[t] = ex;
    if (t == 511) base[512] = buf[pi][511];   // == NE
}

// ---------------- A3: bucket placement with LDS binning ----------------
__global__ __launch_bounds__(512) void bkt_place(const int* __restrict__ src,
                                                 const int* __restrict__ dst,
                                                 int* __restrict__ bnext,
                                                 int* __restrict__ pairs) {
    __shared__ int stage[CHUNK];     // packed src | dstLow<<17
    __shared__ int sbuf[2][512];
    __shared__ int lcnt[512];
    __shared__ int lex[512];
    __shared__ int gbase[512];
    __shared__ int lnext[512];
    int t = threadIdx.x;
    int base = blockIdx.x * CHUNK;
    int end = min(base + CHUNK, NE);
    int cc = end - base;
    lcnt[t] = 0;
    __syncthreads();
    for (int e = base + t; e < end; e += 512) atomicAdd(&lcnt[dst[e] >> 8], 1);
    __syncthreads();
    int v = lcnt[t];
    int pi = 0;
    sbuf[0][t] = v;
    __syncthreads();
    for (int off = 1; off < 512; off <<= 1) {
        int add = (t >= off) ? sbuf[pi][t - off] : 0;
        sbuf[1 - pi][t] = sbuf[pi][t] + add;
        pi ^= 1;
        __syncthreads();
    }
    int ex = sbuf[pi][t] - v;
    lex[t] = ex;
    lnext[t] = ex;
    gbase[t] = v ? atomicAdd(&bnext[t], v) : 0;
    __syncthreads();
    for (int e = base + t; e < end; e += 512) {
        int d = dst[e];
        int b = d >> 8;
        int r = atomicAdd(&lnext[b], 1);
        stage[r] = src[e] | ((d & 255) << 17);
    }
    __syncthreads();
    for (int i = t; i < cc; i += 512) {
        int lo = 0, hi = 511;
        while (lo < hi) {
            int mid = (lo + hi + 1) >> 1;
            if (lex[mid] <= i) lo = mid; else hi = mid - 1;
        }
        pairs[gbase[lo] + (i - lex[lo])] = stage[i];
    }
}

// ---------------- B: per-bucket CSR build + dinv ----------------
__global__ __launch_bounds__(256) void bkt_csr(const int* __restrict__ pairs,
                                               const int* __restrict__ base,
                                               int* __restrict__ next,
                                               float* __restrict__ dinv,
                                               int* __restrict__ esrc) {
    __shared__ int cnt[256];
    __shared__ int sbuf[2][256];
    __shared__ int nxt[256];
    int b = blockIdx.x;
    int e0 = base[b], e1 = base[b + 1];
    int t = threadIdx.x;
    cnt[t] = 0;
    __syncthreads();
    for (int i = e0 + t; i < e1; i += 256) atomicAdd(&cnt[pairs[i] >> 17], 1);
    __syncthreads();
    int v = cnt[t];
    int pi = 0;
    sbuf[0][t] = v;
    __syncthreads();
    for (int off = 1; off < 256; off <<= 1) {
        int add = (t >= off) ? sbuf[pi][t - off] : 0;
        sbuf[1 - pi][t] = sbuf[pi][t] + add;
        pi ^= 1;
        __syncthreads();
    }
    int incl = sbuf[pi][t];
    int node = b * 256 + t;
    if (node < NN) {
        next[node] = e0 + incl;
        dinv[node] = rsqrtf((float)v + 1.0f);
    }
    nxt[t] = e0 + incl - v;
    __syncthreads();
    for (int i = e0 + t; i < e1; i += 256) {
        int w = pairs[i];
        int p = atomicAdd(&nxt[w >> 17], 1);
        esrc[p] = w & 0x1FFFF;
    }
}

// ---------------- fused gather (bf16 operand): agg + self + bias + relu ----------------
// one wave per dst node; two 32-lane halves walk alternate edges; lane m of a
// half covers features (2m, 2m+1) via one dword (bf16 pair) load = 128 B/edge.
__global__ __launch_bounds__(256) void gather_bf16(
        const int* __restrict__ next, const int* __restrict__ esrc,
        const float* __restrict__ dinv, const unsigned* __restrict__ G,
        const float* __restrict__ b, float* __restrict__ outH, int n) {
    int node = (int)((blockIdx.x * blockDim.x + threadIdx.x) >> 6);
    if (node >= n) return;
    int lane = threadIdx.x & 63;
    int half = lane >> 5, m = lane & 31;
    int j0 = node ? next[node - 1] : 0;
    int e1 = next[node];
    float ax = 0.f, ay = 0.f;
    int j = j0 + half;
    for (; j + 6 < e1; j += 8) {
        int s0 = esrc[j], s1 = esrc[j + 2], s2 = esrc[j + 4], s3 = esrc[j + 6];
        unsigned u0 = G[s0 * 32 + m];
        unsigned u1 = G[s1 * 32 + m];
        unsigned u2 = G[s2 * 32 + m];
        unsigned u3 = G[s3 * 32 + m];
        ax += __uint_as_float(u0 << 16) + __uint_as_float(u1 << 16)
            + __uint_as_float(u2 << 16) + __uint_as_float(u3 << 16);
        ay += __uint_as_float(u0 & 0xffff0000u) + __uint_as_float(u1 & 0xffff0000u)
            + __uint_as_float(u2 & 0xffff0000u) + __uint_as_float(u3 & 0xffff0000u);
    }
    for (; j < e1; j += 2) {
        unsigned u = G[esrc[j] * 32 + m];
        ax += __uint_as_float(u << 16);
        ay += __uint_as_float(u & 0xffff0000u);
    }
    ax += __shfl_xor(ax, 32);
    ay += __shfl_xor(ay, 32);
    if (half == 0) {
        float dd = dinv[node];
        unsigned us = G[node * 32 + m];          // self: g = h*dinv -> g*dd = h*dinv^2
        ax += __uint_as_float(us << 16);
        ay += __uint_as_float(us & 0xffff0000u);
        float2 bb = ((const float2*)b)[m];
        float2 o;
        o.x = fmaxf(fmaf(ax, dd, bb.x), 0.f);
        o.y = fmaxf(fmaf(ay, dd, bb.y), 0.f);
        ((float2*)(outH + (size_t)node * 64))[m] = o;
    }
}

// ---------------- GEMM: [n,64]@[64,64] -> bf16 g = acc*dinv ----------------
__global__ __launch_bounds__(256) void gemm64g(const float* __restrict__ X,
                                               const float* __restrict__ W,
                                               const float* __restrict__ dinv,
                                               ushort4* __restrict__ G, int n) {
    __shared__ float4 Ws[64][16];
    __shared__ float  Xs[16][68];
    int tid = threadIdx.x;
    const float4* W4 = (const float4*)W;
    #pragma unroll
    for (int i = tid; i < 64 * 16; i += 256) Ws[i >> 4][i & 15] = W4[i];
    {
        int rr = tid >> 4, q = tid & 15;
        int node = blockIdx.x * 16 + rr;
        float4 v = ((const float4*)(X + (size_t)node * 64))[q];
        *(float4*)&Xs[rr][q * 4] = v;
    }
    __syncthreads();
    int r = tid >> 4, cq = tid & 15;
    float4 acc = {0.f, 0.f, 0.f, 0.f};
    #pragma unroll
    for (int k = 0; k < 64; ++k) {
        float x  = Xs[r][k];
        float4 w = Ws[k][cq];
        acc.x += x * w.x; acc.y += x * w.y; acc.z += x * w.z; acc.w += x * w.w;
    }
    int node = blockIdx.x * 16 + r;
    float dd = dinv[node];
    ushort4 pk;
    pk.x = f2bf(acc.x * dd);
    pk.y = f2bf(acc.y * dd);
    pk.z = f2bf(acc.z * dd);
    pk.w = f2bf(acc.w * dd);
    G[(size_t)node * 16 + cq] = pk;
}

// ---------------- FC head: [n,64] @ [64,16] + b ----------------
__global__ __launch_bounds__(256) void gemmfc(const float* __restrict__ X,
                                              const float* __restrict__ W,
                                              const float* __restrict__ b,
                                              float* __restrict__ out, int n) {
    __shared__ float Ws[64][16];
    __shared__ float Xs[16][65];
    int tid = threadIdx.x;
    #pragma unroll
    for (int i = tid; i < 64 * 16; i += 256) Ws[i >> 4][i & 15] = W[i];
    #pragma unroll
    for (int i = tid; i < 16 * 64; i += 256) {
        int rr = i >> 6, cc = i & 63;
        int nn = blockIdx.x * 16 + rr;
        Xs[rr][cc] = (nn < n) ? X[nn * 64 + cc] : 0.f;
    }
    __syncthreads();
    int col = tid & 15, r = tid >> 4;
    int node = blockIdx.x * 16 + r;
    if (node >= n) return;
    float acc = b[col];
    #pragma unroll
    for (int k = 0; k < 64; ++k) acc += Xs[r][k] * Ws[k][col];
    out[node * 16 + col] = acc;
}

extern "C" void kernel_launch(void* const* d_in, const int* in_sizes, int n_in,
                              void* d_out, int out_size, void* d_ws, size_t ws_size,
                              hipStream_t stream) {
    const float* x   = (const float*)d_in[0];
    const int*   ei  = (const int*)d_in[1];
    const float* W1  = (const float*)d_in[2];
    const float* b1  = (const float*)d_in[3];
    const float* W2  = (const float*)d_in[4];
    const float* b2  = (const float*)d_in[5];
    const float* Wfc = (const float*)d_in[6];
    const float* bfc = (const float*)d_in[7];
    float* out = (float*)d_out;

    const int* src = ei;
    const int* dst = ei + NE;

    // ws: dinv[NN]f | bcnt[512] | bbase[513] | bnext[512] | next[NN] | esrc[NE]
    //     | G [NN*64 bf16 = 12.8MB] | bufB [NN*64 f32 = 25.6MB]     (~45.6 MB)
    // pairs aliases bufB (consumed by bkt_csr before gather-1 writes bufB)
    float*    dinv  = (float*)d_ws;
    int*      bcnt  = (int*)(dinv + NN);
    int*      bbase = bcnt + NBP;
    int*      bnext = bbase + NBP + 1;
    int*      next  = bnext + NBP;
    int*      esrc  = next + NN;
    unsigned* G     = (unsigned*)(esrc + NE);          // NN*32 uints
    float*    bufB  = (float*)(G + (size_t)NN * 32);
    int*      pairs = (int*)bufB;

    // ---- CSR build (two-pass counting sort) ----
    zero_bkt<<<2, 256, 0, stream>>>(bcnt);
    bkt_hist<<<NCHUNK, 256, 0, stream>>>(dst, bcnt);
    bkt_scan<<<1, 512, 0, stream>>>(bcnt, bbase, bnext);
    bkt_place<<<NCHUNK, 512, 0, stream>>>(src, dst, bnext, pairs);
    bkt_csr<<<NB, 256, 0, stream>>>(pairs, bbase, next, dinv, esrc);

    // ---- layer 1 ----
    gemm64g<<<NN / 16, 256, 0, stream>>>(x, W1, dinv, (ushort4*)G, NN);
    gather_bf16<<<(NN * 64) / 256, 256, 0, stream>>>(next, esrc, dinv, G, b1, bufB, NN);

    // ---- layer 2 ----
    gemm64g<<<NN / 16, 256, 0, stream>>>(bufB, W2, dinv, (ushort4*)G, NN);
    gather_bf16<<<(NN * 64) / 256, 256, 0, stream>>>(next, esrc, dinv, G, b2, bufB, NN);

    // ---- FC head ----
    gemmfc<<<NN / 16, 256, 0, stream>>>(bufB, Wfc, bfc, out, NN);
}